// Round 1
// 1049.093 us; speedup vs baseline: 1.0544x; 1.0544x over previous
//
#include <hip/hip_runtime.h>
#include <math.h>

#define NN 100000
#define EE 1600000
#define ET (EE + NN)   // edges + self loops
#define F1 128         // H*C layer1
#define NH 16
#define F2 19

typedef __bf16 bf16x8 __attribute__((ext_vector_type(8)));
typedef float f32x4 __attribute__((ext_vector_type(4)));

#define LDST 40   // LDS row stride in bf16 elems: 80B -> 16B aligned, 2-way bank alias (free)

// ---------------- CSR build ----------------
__global__ __launch_bounds__(256) void deg_kernel(const int* __restrict__ dst, int* __restrict__ deg) {
  int e = blockIdx.x * 256 + threadIdx.x;
  if (e >= ET) return;
  int d = (e < EE) ? dst[e] : (e - EE);
  atomicAdd(&deg[d], 1);
}

// ---- parallel exclusive scan over deg[NN] -> offs, 3 phases ----
#define SCB 391   // ceil(100000/256)
__global__ __launch_bounds__(256) void scan_block(const int* __restrict__ deg, int* __restrict__ offs,
                                                  int* __restrict__ bsum) {
  __shared__ int wsum[4];
  int b = blockIdx.x, tid = threadIdx.x;
  int i = b * 256 + tid;
  int lane = tid & 63, wid = tid >> 6;
  int v = (i < NN) ? deg[i] : 0;
  int x = v;
  #pragma unroll
  for (int off = 1; off < 64; off <<= 1) {
    int t = __shfl_up(x, off, 64);
    if (lane >= off) x += t;
  }
  if (lane == 63) wsum[wid] = x;
  __syncthreads();
  int add = 0;
  #pragma unroll
  for (int w = 0; w < 4; ++w) if (w < wid) add += wsum[w];
  if (i < NN) offs[i] = x + add - v;   // exclusive within block
  if (tid == 255) bsum[b] = x + add;
}

__global__ __launch_bounds__(512) void scan_tops(int* __restrict__ bsum, int* __restrict__ tops,
                                                 int* __restrict__ offs) {
  __shared__ int wsum[8];
  int tid = threadIdx.x;
  int lane = tid & 63, wid = tid >> 6;
  int v = (tid < SCB) ? bsum[tid] : 0;
  int x = v;
  #pragma unroll
  for (int off = 1; off < 64; off <<= 1) {
    int t = __shfl_up(x, off, 64);
    if (lane >= off) x += t;
  }
  if (lane == 63) wsum[wid] = x;
  __syncthreads();
  int add = 0;
  #pragma unroll
  for (int w = 0; w < 8; ++w) if (w < wid) add += wsum[w];
  if (tid < SCB) tops[tid] = x + add - v;   // exclusive scan of block sums
  if (tid == SCB - 1) offs[NN] = x + add;   // grand total == ET
}

__global__ __launch_bounds__(256) void scan_add(int* __restrict__ offs, const int* __restrict__ tops) {
  int i = blockIdx.x * 256 + threadIdx.x;
  if (i < NN) offs[i] += tops[blockIdx.x];
}

__global__ __launch_bounds__(256) void fill_kernel(const int* __restrict__ src, const int* __restrict__ dst,
                                                   const int* __restrict__ offs, int* __restrict__ cnt,
                                                   int* __restrict__ csr) {
  int e = blockIdx.x * 256 + threadIdx.x;
  if (e >= ET) return;
  int d, s;
  if (e < EE) { d = dst[e]; s = src[e]; } else { d = e - EE; s = e - EE; }
  int pos = offs[d] + atomicAdd(&cnt[d], 1);
  csr[pos] = s;
}

// ---------------- W1 split+transpose: Wt_h/Wt_l [128][1024] bf16 ----------------
__global__ __launch_bounds__(256) void wsplit_kernel(const float* __restrict__ W, __bf16* __restrict__ Wth,
                                                     __bf16* __restrict__ Wtl) {
  int idx = blockIdx.x * 256 + threadIdx.x;   // k*128 + n
  if (idx >= 1024 * 128) return;
  int k = idx >> 7, n = idx & 127;
  float v = W[idx];
  __bf16 h = (__bf16)v;
  __bf16 l = (__bf16)(v - (float)h);
  Wth[(size_t)n * 1024 + k] = h;
  Wtl[(size_t)n * 1024 + k] = l;
}

// ---------------- GEMM1: h1 = x @ W1 via bf16x3 MFMA (M=1e5, K=1024, N=128) ----------------
__global__ __launch_bounds__(256) void gemm1_mfma(const float* __restrict__ X, const __bf16* __restrict__ Wth,
                                                  const __bf16* __restrict__ Wtl, float* __restrict__ H1, int M) {
  __shared__ __bf16 Ah[128 * LDST];
  __shared__ __bf16 Al[128 * LDST];
  __shared__ __bf16 Bh[128 * LDST];
  __shared__ __bf16 Bl[128 * LDST];
  const int tid = threadIdx.x;
  const int m0 = blockIdx.x * 128;
  const int wv = tid >> 6, lane = tid & 63;
  const int lrow = lane & 15, quad = lane >> 4;
  const int sr = tid >> 1;
  const int sk = (tid & 1) * 16;
  int grow = m0 + sr; if (grow > M - 1) grow = M - 1;
  const float* xrow = &X[(size_t)grow * 1024];
  const __bf16* wthr = &Wth[(size_t)sr * 1024];
  const __bf16* wtlr = &Wtl[(size_t)sr * 1024];

  f32x4 acc[2][8];
  #pragma unroll
  for (int i = 0; i < 2; ++i)
    #pragma unroll
    for (int j = 0; j < 8; ++j) acc[i][j] = (f32x4){0.f, 0.f, 0.f, 0.f};

  for (int k0 = 0; k0 < 1024; k0 += 32) {
    float tmp[16];
    {
      const float4 v0 = *reinterpret_cast<const float4*>(&xrow[k0 + sk + 0]);
      const float4 v1 = *reinterpret_cast<const float4*>(&xrow[k0 + sk + 4]);
      const float4 v2 = *reinterpret_cast<const float4*>(&xrow[k0 + sk + 8]);
      const float4 v3 = *reinterpret_cast<const float4*>(&xrow[k0 + sk + 12]);
      tmp[0] = v0.x; tmp[1] = v0.y; tmp[2] = v0.z; tmp[3] = v0.w;
      tmp[4] = v1.x; tmp[5] = v1.y; tmp[6] = v1.z; tmp[7] = v1.w;
      tmp[8] = v2.x; tmp[9] = v2.y; tmp[10] = v2.z; tmp[11] = v2.w;
      tmp[12] = v3.x; tmp[13] = v3.y; tmp[14] = v3.z; tmp[15] = v3.w;
    }
    bf16x8 hv0, hv1, lv0, lv1;
    #pragma unroll
    for (int j = 0; j < 8; ++j) {
      __bf16 h = (__bf16)tmp[j];
      hv0[j] = h; lv0[j] = (__bf16)(tmp[j] - (float)h);
    }
    #pragma unroll
    for (int j = 0; j < 8; ++j) {
      __bf16 h = (__bf16)tmp[8 + j];
      hv1[j] = h; lv1[j] = (__bf16)(tmp[8 + j] - (float)h);
    }
    *reinterpret_cast<bf16x8*>(&Ah[sr * LDST + sk]) = hv0;
    *reinterpret_cast<bf16x8*>(&Ah[sr * LDST + sk + 8]) = hv1;
    *reinterpret_cast<bf16x8*>(&Al[sr * LDST + sk]) = lv0;
    *reinterpret_cast<bf16x8*>(&Al[sr * LDST + sk + 8]) = lv1;
    {
      bf16x8 b0 = *reinterpret_cast<const bf16x8*>(&wthr[k0 + sk]);
      bf16x8 b1 = *reinterpret_cast<const bf16x8*>(&wthr[k0 + sk + 8]);
      bf16x8 c0 = *reinterpret_cast<const bf16x8*>(&wtlr[k0 + sk]);
      bf16x8 c1 = *reinterpret_cast<const bf16x8*>(&wtlr[k0 + sk + 8]);
      *reinterpret_cast<bf16x8*>(&Bh[sr * LDST + sk]) = b0;
      *reinterpret_cast<bf16x8*>(&Bh[sr * LDST + sk + 8]) = b1;
      *reinterpret_cast<bf16x8*>(&Bl[sr * LDST + sk]) = c0;
      *reinterpret_cast<bf16x8*>(&Bl[sr * LDST + sk + 8]) = c1;
    }
    __syncthreads();
    bf16x8 afh[2], afl[2];
    #pragma unroll
    for (int mt = 0; mt < 2; ++mt) {
      int r = wv * 32 + mt * 16 + lrow;
      afh[mt] = *reinterpret_cast<const bf16x8*>(&Ah[r * LDST + quad * 8]);
      afl[mt] = *reinterpret_cast<const bf16x8*>(&Al[r * LDST + quad * 8]);
    }
    #pragma unroll
    for (int nt = 0; nt < 8; ++nt) {
      int r = nt * 16 + lrow;
      bf16x8 bfh = *reinterpret_cast<const bf16x8*>(&Bh[r * LDST + quad * 8]);
      bf16x8 bfl = *reinterpret_cast<const bf16x8*>(&Bl[r * LDST + quad * 8]);
      #pragma unroll
      for (int mt = 0; mt < 2; ++mt) {
        acc[mt][nt] = __builtin_amdgcn_mfma_f32_16x16x32_bf16(afh[mt], bfh, acc[mt][nt], 0, 0, 0);
        acc[mt][nt] = __builtin_amdgcn_mfma_f32_16x16x32_bf16(afl[mt], bfh, acc[mt][nt], 0, 0, 0);
        acc[mt][nt] = __builtin_amdgcn_mfma_f32_16x16x32_bf16(afh[mt], bfl, acc[mt][nt], 0, 0, 0);
      }
    }
    __syncthreads();
  }
  #pragma unroll
  for (int mt = 0; mt < 2; ++mt) {
    #pragma unroll
    for (int r = 0; r < 4; ++r) {
      int row = m0 + wv * 32 + mt * 16 + quad * 4 + r;
      if (row < M) {
        #pragma unroll
        for (int nt = 0; nt < 8; ++nt) {
          H1[(size_t)row * 128 + nt * 16 + lrow] = acc[mt][nt][r];
        }
      }
    }
  }
}

// ---------------- attention scalars layer 1 (float4 loads) ----------------
__global__ __launch_bounds__(256) void a1_kernel(const float* __restrict__ h1, const float* __restrict__ att_s,
                                                 const float* __restrict__ att_d, float* __restrict__ a_src,
                                                 float* __restrict__ a_dst) {
  int idx = blockIdx.x * 256 + threadIdx.x;   // n*16 + h
  if (idx >= NN * NH) return;
  int h = idx & 15;
  const float4 v0 = *reinterpret_cast<const float4*>(&h1[(size_t)idx * 8]);
  const float4 v1 = *reinterpret_cast<const float4*>(&h1[(size_t)idx * 8 + 4]);
  const float4 s0 = *reinterpret_cast<const float4*>(&att_s[h * 8]);
  const float4 s1 = *reinterpret_cast<const float4*>(&att_s[h * 8 + 4]);
  const float4 d0 = *reinterpret_cast<const float4*>(&att_d[h * 8]);
  const float4 d1 = *reinterpret_cast<const float4*>(&att_d[h * 8 + 4]);
  float s = v0.x * s0.x + v0.y * s0.y + v0.z * s0.z + v0.w * s0.w
          + v1.x * s1.x + v1.y * s1.y + v1.z * s1.z + v1.w * s1.w;
  float d = v0.x * d0.x + v0.y * d0.y + v0.z * d0.z + v0.w * d0.w
          + v1.x * d1.x + v1.y * d1.y + v1.z * d1.z + v1.w * d1.w;
  a_src[idx] = s; a_dst[idx] = d;
}

// ---------------- layer1 aggregation: wave-per-node, single-pass softmax (no max subtraction) ----
// exp(a-m)/sum(exp(a-m)) == exp(a)/sum(exp(a)); scores are O(10) so exp() is safe in fp32.
// 4-edge unroll -> 4 independent csr->a_src->h1 load chains in flight per lane.
__global__ __launch_bounds__(256) void agg1_kernel(const float* __restrict__ h1, const float* __restrict__ a_src,
                                                   const float* __restrict__ a_dst, const int* __restrict__ offs,
                                                   const int* __restrict__ csr, const float* __restrict__ b1,
                                                   float* __restrict__ act1) {
  const int wid = threadIdx.x >> 6, lane = threadIdx.x & 63;
  const int n = blockIdx.x * 4 + wid;
  if (n >= NN) return;
  const int beg = offs[n], end = offs[n + 1];
  const int h = lane >> 2;                 // head owning channels 2*lane, 2*lane+1
  const int c2 = lane * 2;
  const float adst = a_dst[n * NH + h];
  float2 acc0 = {0.f, 0.f}, acc1 = {0.f, 0.f}, acc2 = {0.f, 0.f}, acc3 = {0.f, 0.f};
  float ls0 = 0.f, ls1 = 0.f, ls2 = 0.f, ls3 = 0.f;
  int e = beg;
  for (; e + 3 < end; e += 4) {
    int s0 = csr[e], s1 = csr[e + 1], s2 = csr[e + 2], s3 = csr[e + 3];
    float a0 = a_src[s0 * NH + h] + adst;
    float a1 = a_src[s1 * NH + h] + adst;
    float a2 = a_src[s2 * NH + h] + adst;
    float a3 = a_src[s3 * NH + h] + adst;
    a0 = a0 > 0.f ? a0 : 0.2f * a0;
    a1 = a1 > 0.f ? a1 : 0.2f * a1;
    a2 = a2 > 0.f ? a2 : 0.2f * a2;
    a3 = a3 > 0.f ? a3 : 0.2f * a3;
    float w0 = __expf(a0), w1 = __expf(a1), w2 = __expf(a2), w3 = __expf(a3);
    float2 hv0 = *reinterpret_cast<const float2*>(&h1[(size_t)s0 * 128 + c2]);
    float2 hv1 = *reinterpret_cast<const float2*>(&h1[(size_t)s1 * 128 + c2]);
    float2 hv2 = *reinterpret_cast<const float2*>(&h1[(size_t)s2 * 128 + c2]);
    float2 hv3 = *reinterpret_cast<const float2*>(&h1[(size_t)s3 * 128 + c2]);
    ls0 += w0; ls1 += w1; ls2 += w2; ls3 += w3;
    acc0.x += w0 * hv0.x; acc0.y += w0 * hv0.y;
    acc1.x += w1 * hv1.x; acc1.y += w1 * hv1.y;
    acc2.x += w2 * hv2.x; acc2.y += w2 * hv2.y;
    acc3.x += w3 * hv3.x; acc3.y += w3 * hv3.y;
  }
  for (; e < end; ++e) {
    int s0 = csr[e];
    float a0 = a_src[s0 * NH + h] + adst;
    a0 = a0 > 0.f ? a0 : 0.2f * a0;
    float w0 = __expf(a0);
    float2 hv0 = *reinterpret_cast<const float2*>(&h1[(size_t)s0 * 128 + c2]);
    ls0 += w0;
    acc0.x += w0 * hv0.x; acc0.y += w0 * hv0.y;
  }
  float lsum = (ls0 + ls1) + (ls2 + ls3);
  float inv = 1.f / (lsum + 1e-16f);
  float ox = ((acc0.x + acc1.x) + (acc2.x + acc3.x)) * inv + b1[c2];
  float oy = ((acc0.y + acc1.y) + (acc2.y + acc3.y)) * inv + b1[c2 + 1];
  float2 o;
  o.x = ox > 0.f ? ox : expm1f(ox);
  o.y = oy > 0.f ? oy : expm1f(oy);
  *reinterpret_cast<float2*>(&act1[(size_t)n * 128 + c2]) = o;
}

// ---------------- GEMM2: h2 = act1 @ W2  (K=128, N=19) ----------------
__global__ __launch_bounds__(256) void gemm2_kernel(const float* __restrict__ A, const float* __restrict__ W2,
                                                    float* __restrict__ H2) {
  __shared__ float Ws[128 * 19];
  for (int i = threadIdx.x; i < 128 * 19; i += 256) Ws[i] = W2[i];
  __syncthreads();
  int idx = blockIdx.x * 256 + threadIdx.x;
  if (idx >= NN * F2) return;
  int row = idx / F2, col = idx % F2;
  const float* a = &A[(size_t)row * 128];
  float s = 0.f;
  #pragma unroll 8
  for (int k = 0; k < 128; ++k) s += a[k] * Ws[k * F2 + col];
  H2[idx] = s;
}

// ---------------- attention scalars layer 2 ----------------
__global__ __launch_bounds__(256) void a2_kernel(const float* __restrict__ h2, const float* __restrict__ att_s,
                                                 const float* __restrict__ att_d, float* __restrict__ a_src,
                                                 float* __restrict__ a_dst) {
  int n = blockIdx.x * 256 + threadIdx.x;
  if (n >= NN) return;
  const float* hp = &h2[(size_t)n * F2];
  float s = 0.f, d = 0.f;
  #pragma unroll
  for (int c = 0; c < F2; ++c) {
    float v = hp[c];
    s += v * att_s[c];
    d += v * att_d[c];
  }
  a_src[n] = s; a_dst[n] = d;
}

// ---------------- layer2 aggregation + bias + log_softmax: single-pass softmax ----------------
__global__ __launch_bounds__(256) void agg2_kernel(const float* __restrict__ h2, const float* __restrict__ a_src,
                                                   const float* __restrict__ a_dst, const int* __restrict__ offs,
                                                   const int* __restrict__ csr, const float* __restrict__ b2,
                                                   float* __restrict__ out) {
  const int wid = threadIdx.x >> 6, lane = threadIdx.x & 63;
  const int n = blockIdx.x * 4 + wid;
  if (n >= NN) return;
  const int beg = offs[n], end = offs[n + 1];
  const float adst = a_dst[n];
  // lanes 0..56 = (group g=lane/19, channel c=lane%19), 3 edge-groups, 2-edge unroll per group
  const int g = lane / 19;          // 0..3 (g==3 idle)
  const int c = lane - g * 19;
  float acc = 0.f, ls = 0.f;
  if (g < 3) {
    int e = beg + g;
    for (; e + 3 < end; e += 6) {   // this group's edges: e and e+3
      int s0 = csr[e], s1 = csr[e + 3];
      float a0 = a_src[s0] + adst;
      float a1 = a_src[s1] + adst;
      a0 = a0 > 0.f ? a0 : 0.2f * a0;
      a1 = a1 > 0.f ? a1 : 0.2f * a1;
      float w0 = __expf(a0), w1 = __expf(a1);
      float v0 = h2[(size_t)s0 * F2 + c];
      float v1 = h2[(size_t)s1 * F2 + c];
      ls += w0 + w1;
      acc += w0 * v0 + w1 * v1;
    }
    if (e < end) {
      int s0 = csr[e];
      float a0 = a_src[s0] + adst;
      a0 = a0 > 0.f ? a0 : 0.2f * a0;
      float w0 = __expf(a0);
      ls += w0;
      acc += w0 * h2[(size_t)s0 * F2 + c];
    }
  }
  // merge the 3 groups: lane c collects from lanes c, c+19, c+38
  float acc_t = __shfl(acc, c, 64) + __shfl(acc, c + 19, 64) + __shfl(acc, c + 38, 64);
  float ls_t  = __shfl(ls, c, 64) + __shfl(ls, c + 19, 64) + __shfl(ls, c + 38, 64);
  const bool act = lane < F2;
  float o = acc_t / (ls_t + 1e-16f) + (act ? b2[lane] : 0.f);
  // log_softmax across lanes 0..18 (use lanes 0..31 reduce)
  float v = act ? o : -INFINITY;
  float mx = v;
  #pragma unroll
  for (int off = 16; off >= 1; off >>= 1) mx = fmaxf(mx, __shfl_xor(mx, off, 32));
  float se = act ? __expf(v - mx) : 0.f;
  float sum = se;
  #pragma unroll
  for (int off = 16; off >= 1; off >>= 1) sum += __shfl_xor(sum, off, 32);
  if (act) out[(size_t)n * F2 + lane] = (o - mx) - logf(sum);
}

extern "C" void kernel_launch(void* const* d_in, const int* in_sizes, int n_in,
                              void* d_out, int out_size, void* d_ws, size_t ws_size,
                              hipStream_t stream) {
  const float* x   = (const float*)d_in[0];
  const int* ei    = (const int*)d_in[1];
  const float* W1  = (const float*)d_in[2];
  const float* as1 = (const float*)d_in[3];
  const float* ad1 = (const float*)d_in[4];
  const float* b1  = (const float*)d_in[5];
  const float* W2  = (const float*)d_in[6];
  const float* as2 = (const float*)d_in[7];
  const float* ad2 = (const float*)d_in[8];
  const float* b2  = (const float*)d_in[9];
  float* out = (float*)d_out;

  const int* srcp = ei;
  const int* dstp = ei + EE;

  char* p = (char*)d_ws;
  auto alloc = [&](size_t bytes) { char* r = p; p += (bytes + 255) & ~(size_t)255; return r; };
  float* h1    = (float*)alloc((size_t)NN * F1 * 4);
  float* act1  = (float*)alloc((size_t)NN * F1 * 4);
  float* a_s1  = (float*)alloc((size_t)NN * NH * 4);
  float* a_d1  = (float*)alloc((size_t)NN * NH * 4);
  float* h2    = (float*)alloc((size_t)NN * F2 * 4);
  float* a_s2  = (float*)alloc((size_t)NN * 4);
  float* a_d2  = (float*)alloc((size_t)NN * 4);
  int*   deg   = (int*)alloc((size_t)NN * 4);
  int*   offs  = (int*)alloc((size_t)(NN + 1) * 4);
  int*   cnt   = (int*)alloc((size_t)NN * 4);
  int*   csr   = (int*)alloc((size_t)ET * 4);
  int*   bsum  = (int*)alloc((size_t)SCB * 4);
  int*   tops  = (int*)alloc((size_t)SCB * 4);
  __bf16* Wth  = (__bf16*)alloc((size_t)128 * 1024 * 2);
  __bf16* Wtl  = (__bf16*)alloc((size_t)128 * 1024 * 2);

  hipMemsetAsync(deg, 0, (size_t)NN * 4, stream);
  hipMemsetAsync(cnt, 0, (size_t)NN * 4, stream);

  int eb = (ET + 255) / 256;
  deg_kernel<<<eb, 256, 0, stream>>>(dstp, deg);
  scan_block<<<SCB, 256, 0, stream>>>(deg, offs, bsum);
  scan_tops<<<1, 512, 0, stream>>>(bsum, tops, offs);
  scan_add<<<SCB, 256, 0, stream>>>(offs, tops);
  fill_kernel<<<eb, 256, 0, stream>>>(srcp, dstp, offs, cnt, csr);

  wsplit_kernel<<<(1024 * 128 + 255) / 256, 256, 0, stream>>>(W1, Wth, Wtl);
  gemm1_mfma<<<(NN + 127) / 128, 256, 0, stream>>>(x, Wth, Wtl, h1, NN);
  a1_kernel<<<(NN * NH + 255) / 256, 256, 0, stream>>>(h1, as1, ad1, a_s1, a_d1);
  agg1_kernel<<<(NN + 3) / 4, 256, 0, stream>>>(h1, a_s1, a_d1, offs, csr, b1, act1);

  gemm2_kernel<<<(NN * F2 + 255) / 256, 256, 0, stream>>>(act1, W2, h2);
  a2_kernel<<<(NN + 255) / 256, 256, 0, stream>>>(h2, as2, ad2, a_s2, a_d2);
  agg2_kernel<<<(NN + 3) / 4, 256, 0, stream>>>(h2, a_s2, a_d2, offs, csr, b2, out);
}

// Round 2
// 966.022 us; speedup vs baseline: 1.1451x; 1.0860x over previous
//
#include <hip/hip_runtime.h>
#include <math.h>

#define NN 100000
#define EE 1600000
#define ET (EE + NN)   // edges + self loops
#define F1 128         // H*C layer1
#define NH 16
#define F2 19

typedef __bf16 bf16x8 __attribute__((ext_vector_type(8)));
typedef float f32x4 __attribute__((ext_vector_type(4)));
typedef _Float16 f16x2 __attribute__((ext_vector_type(2)));
typedef _Float16 f16x8 __attribute__((ext_vector_type(8)));

#define LDST 40   // LDS row stride in bf16 elems: 80B -> 16B aligned, 2-way bank alias (free)

// ---------------- CSR build ----------------
__global__ __launch_bounds__(256) void deg_kernel(const int* __restrict__ dst, int* __restrict__ deg) {
  int e = blockIdx.x * 256 + threadIdx.x;
  if (e >= ET) return;
  int d = (e < EE) ? dst[e] : (e - EE);
  atomicAdd(&deg[d], 1);
}

// ---- parallel exclusive scan over deg[NN] -> offs, 3 phases ----
#define SCB 391   // ceil(100000/256)
__global__ __launch_bounds__(256) void scan_block(const int* __restrict__ deg, int* __restrict__ offs,
                                                  int* __restrict__ bsum) {
  __shared__ int wsum[4];
  int b = blockIdx.x, tid = threadIdx.x;
  int i = b * 256 + tid;
  int lane = tid & 63, wid = tid >> 6;
  int v = (i < NN) ? deg[i] : 0;
  int x = v;
  #pragma unroll
  for (int off = 1; off < 64; off <<= 1) {
    int t = __shfl_up(x, off, 64);
    if (lane >= off) x += t;
  }
  if (lane == 63) wsum[wid] = x;
  __syncthreads();
  int add = 0;
  #pragma unroll
  for (int w = 0; w < 4; ++w) if (w < wid) add += wsum[w];
  if (i < NN) offs[i] = x + add - v;   // exclusive within block
  if (tid == 255) bsum[b] = x + add;
}

__global__ __launch_bounds__(512) void scan_tops(int* __restrict__ bsum, int* __restrict__ tops,
                                                 int* __restrict__ offs) {
  __shared__ int wsum[8];
  int tid = threadIdx.x;
  int lane = tid & 63, wid = tid >> 6;
  int v = (tid < SCB) ? bsum[tid] : 0;
  int x = v;
  #pragma unroll
  for (int off = 1; off < 64; off <<= 1) {
    int t = __shfl_up(x, off, 64);
    if (lane >= off) x += t;
  }
  if (lane == 63) wsum[wid] = x;
  __syncthreads();
  int add = 0;
  #pragma unroll
  for (int w = 0; w < 8; ++w) if (w < wid) add += wsum[w];
  if (tid < SCB) tops[tid] = x + add - v;   // exclusive scan of block sums
  if (tid == SCB - 1) offs[NN] = x + add;   // grand total == ET
}

__global__ __launch_bounds__(256) void scan_add(int* __restrict__ offs, const int* __restrict__ tops) {
  int i = blockIdx.x * 256 + threadIdx.x;
  if (i < NN) offs[i] += tops[blockIdx.x];
}

__global__ __launch_bounds__(256) void fill_kernel(const int* __restrict__ src, const int* __restrict__ dst,
                                                   const int* __restrict__ offs, int* __restrict__ cnt,
                                                   int* __restrict__ csr) {
  int e = blockIdx.x * 256 + threadIdx.x;
  if (e >= ET) return;
  int d, s;
  if (e < EE) { d = dst[e]; s = src[e]; } else { d = e - EE; s = e - EE; }
  int pos = offs[d] + atomicAdd(&cnt[d], 1);
  csr[pos] = s;
}

// ---------------- W1 split+transpose: Wt_h/Wt_l [128][1024] bf16 ----------------
__global__ __launch_bounds__(256) void wsplit_kernel(const float* __restrict__ W, __bf16* __restrict__ Wth,
                                                     __bf16* __restrict__ Wtl) {
  int idx = blockIdx.x * 256 + threadIdx.x;   // k*128 + n
  if (idx >= 1024 * 128) return;
  int k = idx >> 7, n = idx & 127;
  float v = W[idx];
  __bf16 h = (__bf16)v;
  __bf16 l = (__bf16)(v - (float)h);
  Wth[(size_t)n * 1024 + k] = h;
  Wtl[(size_t)n * 1024 + k] = l;
}

// ---------------- GEMM1: h1 = x @ W1 via bf16x3 MFMA (M=1e5, K=1024, N=128) ----------------
// A operand: direct global->register (rows are wave-exclusive), converted in-register.
// Only B (Wth/Wtl) is LDS-staged. LDS ops per thread per K-step: 28 -> 20 b128-equiv.
__global__ __launch_bounds__(256) void gemm1_mfma(const float* __restrict__ X, const __bf16* __restrict__ Wth,
                                                  const __bf16* __restrict__ Wtl, float* __restrict__ H1, int M) {
  __shared__ __bf16 Bh[128 * LDST];
  __shared__ __bf16 Bl[128 * LDST];
  const int tid = threadIdx.x;
  const int m0 = blockIdx.x * 128;
  const int wv = tid >> 6, lane = tid & 63;
  const int lrow = lane & 15, quad = lane >> 4;
  const int sr = tid >> 1;
  const int sk = (tid & 1) * 16;
  const __bf16* wthr = &Wth[(size_t)sr * 1024];
  const __bf16* wtlr = &Wtl[(size_t)sr * 1024];

  // per-wave A row pointers (fragment layout: lane(lrow,quad) -> row base+lrow, cols k0+quad*8..+7)
  const float* arow[2];
  #pragma unroll
  for (int mt = 0; mt < 2; ++mt) {
    int r = m0 + wv * 32 + mt * 16 + lrow;
    if (r > M - 1) r = M - 1;
    arow[mt] = &X[(size_t)r * 1024 + quad * 8];
  }

  f32x4 acc[2][8];
  #pragma unroll
  for (int i = 0; i < 2; ++i)
    #pragma unroll
    for (int j = 0; j < 8; ++j) acc[i][j] = (f32x4){0.f, 0.f, 0.f, 0.f};

  float4 av0[2], av1[2];
  #pragma unroll
  for (int mt = 0; mt < 2; ++mt) {
    av0[mt] = *reinterpret_cast<const float4*>(&arow[mt][0]);
    av1[mt] = *reinterpret_cast<const float4*>(&arow[mt][4]);
  }

  for (int k0 = 0; k0 < 1024; k0 += 32) {
    // ---- stage B tile to LDS ----
    {
      bf16x8 b0 = *reinterpret_cast<const bf16x8*>(&wthr[k0 + sk]);
      bf16x8 b1 = *reinterpret_cast<const bf16x8*>(&wthr[k0 + sk + 8]);
      bf16x8 c0 = *reinterpret_cast<const bf16x8*>(&wtlr[k0 + sk]);
      bf16x8 c1 = *reinterpret_cast<const bf16x8*>(&wtlr[k0 + sk + 8]);
      *reinterpret_cast<bf16x8*>(&Bh[sr * LDST + sk]) = b0;
      *reinterpret_cast<bf16x8*>(&Bh[sr * LDST + sk + 8]) = b1;
      *reinterpret_cast<bf16x8*>(&Bl[sr * LDST + sk]) = c0;
      *reinterpret_cast<bf16x8*>(&Bl[sr * LDST + sk + 8]) = c1;
    }
    // ---- convert current A regs to hi/lo fragments ----
    bf16x8 afh[2], afl[2];
    #pragma unroll
    for (int mt = 0; mt < 2; ++mt) {
      float t[8] = {av0[mt].x, av0[mt].y, av0[mt].z, av0[mt].w,
                    av1[mt].x, av1[mt].y, av1[mt].z, av1[mt].w};
      #pragma unroll
      for (int j = 0; j < 8; ++j) {
        __bf16 h = (__bf16)t[j];
        afh[mt][j] = h;
        afl[mt][j] = (__bf16)(t[j] - (float)h);
      }
    }
    // ---- prefetch next A (hides HBM latency under MFMAs) ----
    if (k0 + 32 < 1024) {
      #pragma unroll
      for (int mt = 0; mt < 2; ++mt) {
        av0[mt] = *reinterpret_cast<const float4*>(&arow[mt][k0 + 32]);
        av1[mt] = *reinterpret_cast<const float4*>(&arow[mt][k0 + 36]);
      }
    }
    __syncthreads();
    #pragma unroll
    for (int nt = 0; nt < 8; ++nt) {
      int r = nt * 16 + lrow;
      bf16x8 bfh = *reinterpret_cast<const bf16x8*>(&Bh[r * LDST + quad * 8]);
      bf16x8 bfl = *reinterpret_cast<const bf16x8*>(&Bl[r * LDST + quad * 8]);
      #pragma unroll
      for (int mt = 0; mt < 2; ++mt) {
        acc[mt][nt] = __builtin_amdgcn_mfma_f32_16x16x32_bf16(afh[mt], bfh, acc[mt][nt], 0, 0, 0);
        acc[mt][nt] = __builtin_amdgcn_mfma_f32_16x16x32_bf16(afl[mt], bfh, acc[mt][nt], 0, 0, 0);
        acc[mt][nt] = __builtin_amdgcn_mfma_f32_16x16x32_bf16(afh[mt], bfl, acc[mt][nt], 0, 0, 0);
      }
    }
    __syncthreads();
  }
  #pragma unroll
  for (int mt = 0; mt < 2; ++mt) {
    #pragma unroll
    for (int r = 0; r < 4; ++r) {
      int row = m0 + wv * 32 + mt * 16 + quad * 4 + r;
      if (row < M) {
        #pragma unroll
        for (int nt = 0; nt < 8; ++nt) {
          H1[(size_t)row * 128 + nt * 16 + lrow] = acc[mt][nt][r];
        }
      }
    }
  }
}

// ---------------- attention scalars layer 1 (float4 loads) + fp16 copy of h1 ----------------
__global__ __launch_bounds__(256) void a1_kernel(const float* __restrict__ h1, const float* __restrict__ att_s,
                                                 const float* __restrict__ att_d, float* __restrict__ a_src,
                                                 float* __restrict__ a_dst, _Float16* __restrict__ h1h) {
  int idx = blockIdx.x * 256 + threadIdx.x;   // n*16 + h
  if (idx >= NN * NH) return;
  int h = idx & 15;
  const float4 v0 = *reinterpret_cast<const float4*>(&h1[(size_t)idx * 8]);
  const float4 v1 = *reinterpret_cast<const float4*>(&h1[(size_t)idx * 8 + 4]);
  const float4 s0 = *reinterpret_cast<const float4*>(&att_s[h * 8]);
  const float4 s1 = *reinterpret_cast<const float4*>(&att_s[h * 8 + 4]);
  const float4 d0 = *reinterpret_cast<const float4*>(&att_d[h * 8]);
  const float4 d1 = *reinterpret_cast<const float4*>(&att_d[h * 8 + 4]);
  float s = v0.x * s0.x + v0.y * s0.y + v0.z * s0.z + v0.w * s0.w
          + v1.x * s1.x + v1.y * s1.y + v1.z * s1.z + v1.w * s1.w;
  float d = v0.x * d0.x + v0.y * d0.y + v0.z * d0.z + v0.w * d0.w
          + v1.x * d1.x + v1.y * d1.y + v1.z * d1.z + v1.w * d1.w;
  a_src[idx] = s; a_dst[idx] = d;
  f16x8 hv;
  hv[0] = (_Float16)v0.x; hv[1] = (_Float16)v0.y; hv[2] = (_Float16)v0.z; hv[3] = (_Float16)v0.w;
  hv[4] = (_Float16)v1.x; hv[5] = (_Float16)v1.y; hv[6] = (_Float16)v1.z; hv[7] = (_Float16)v1.w;
  *reinterpret_cast<f16x8*>(&h1h[(size_t)idx * 8]) = hv;
}

// ---------------- layer1 aggregation: wave-per-node, single-pass softmax, fp16 feature gather ----
__global__ __launch_bounds__(256) void agg1_kernel(const _Float16* __restrict__ h1h, const float* __restrict__ a_src,
                                                   const float* __restrict__ a_dst, const int* __restrict__ offs,
                                                   const int* __restrict__ csr, const float* __restrict__ b1,
                                                   _Float16* __restrict__ act1) {
  const int wid = threadIdx.x >> 6, lane = threadIdx.x & 63;
  const int n = blockIdx.x * 4 + wid;
  if (n >= NN) return;
  const int beg = offs[n], end = offs[n + 1];
  const int h = lane >> 2;                 // head owning channels 2*lane, 2*lane+1
  const int c2 = lane * 2;
  const float adst = a_dst[n * NH + h];
  float2 acc0 = {0.f, 0.f}, acc1 = {0.f, 0.f}, acc2 = {0.f, 0.f}, acc3 = {0.f, 0.f};
  float ls0 = 0.f, ls1 = 0.f, ls2 = 0.f, ls3 = 0.f;
  int e = beg;
  for (; e + 3 < end; e += 4) {
    int s0 = csr[e], s1 = csr[e + 1], s2 = csr[e + 2], s3 = csr[e + 3];
    float a0 = a_src[s0 * NH + h] + adst;
    float a1 = a_src[s1 * NH + h] + adst;
    float a2 = a_src[s2 * NH + h] + adst;
    float a3 = a_src[s3 * NH + h] + adst;
    a0 = a0 > 0.f ? a0 : 0.2f * a0;
    a1 = a1 > 0.f ? a1 : 0.2f * a1;
    a2 = a2 > 0.f ? a2 : 0.2f * a2;
    a3 = a3 > 0.f ? a3 : 0.2f * a3;
    float w0 = __expf(a0), w1 = __expf(a1), w2 = __expf(a2), w3 = __expf(a3);
    f16x2 hv0 = *reinterpret_cast<const f16x2*>(&h1h[(size_t)s0 * 128 + c2]);
    f16x2 hv1 = *reinterpret_cast<const f16x2*>(&h1h[(size_t)s1 * 128 + c2]);
    f16x2 hv2 = *reinterpret_cast<const f16x2*>(&h1h[(size_t)s2 * 128 + c2]);
    f16x2 hv3 = *reinterpret_cast<const f16x2*>(&h1h[(size_t)s3 * 128 + c2]);
    ls0 += w0; ls1 += w1; ls2 += w2; ls3 += w3;
    acc0.x += w0 * (float)hv0[0]; acc0.y += w0 * (float)hv0[1];
    acc1.x += w1 * (float)hv1[0]; acc1.y += w1 * (float)hv1[1];
    acc2.x += w2 * (float)hv2[0]; acc2.y += w2 * (float)hv2[1];
    acc3.x += w3 * (float)hv3[0]; acc3.y += w3 * (float)hv3[1];
  }
  for (; e < end; ++e) {
    int s0 = csr[e];
    float a0 = a_src[s0 * NH + h] + adst;
    a0 = a0 > 0.f ? a0 : 0.2f * a0;
    float w0 = __expf(a0);
    f16x2 hv0 = *reinterpret_cast<const f16x2*>(&h1h[(size_t)s0 * 128 + c2]);
    ls0 += w0;
    acc0.x += w0 * (float)hv0[0]; acc0.y += w0 * (float)hv0[1];
  }
  float lsum = (ls0 + ls1) + (ls2 + ls3);
  float inv = 1.f / (lsum + 1e-16f);
  float ox = ((acc0.x + acc1.x) + (acc2.x + acc3.x)) * inv + b1[c2];
  float oy = ((acc0.y + acc1.y) + (acc2.y + acc3.y)) * inv + b1[c2 + 1];
  ox = ox > 0.f ? ox : expm1f(ox);
  oy = oy > 0.f ? oy : expm1f(oy);
  f16x2 o;
  o[0] = (_Float16)ox; o[1] = (_Float16)oy;
  *reinterpret_cast<f16x2*>(&act1[(size_t)n * 128 + c2]) = o;
}

// ---------------- GEMM2: h2 = act1 @ W2  (K=128, N=19), fp16 in/out ----------------
__global__ __launch_bounds__(256) void gemm2_kernel(const _Float16* __restrict__ A, const float* __restrict__ W2,
                                                    _Float16* __restrict__ H2) {
  __shared__ float Ws[128 * 19];
  for (int i = threadIdx.x; i < 128 * 19; i += 256) Ws[i] = W2[i];
  __syncthreads();
  int idx = blockIdx.x * 256 + threadIdx.x;
  if (idx >= NN * F2) return;
  int row = idx / F2, col = idx % F2;
  const f16x2* a = reinterpret_cast<const f16x2*>(&A[(size_t)row * 128]);
  float s = 0.f;
  #pragma unroll 8
  for (int k = 0; k < 64; ++k) {
    f16x2 v = a[k];
    s += (float)v[0] * Ws[(2 * k) * F2 + col] + (float)v[1] * Ws[(2 * k + 1) * F2 + col];
  }
  H2[idx] = (_Float16)s;
}

// ---------------- attention scalars layer 2 ----------------
__global__ __launch_bounds__(256) void a2_kernel(const _Float16* __restrict__ h2, const float* __restrict__ att_s,
                                                 const float* __restrict__ att_d, float* __restrict__ a_src,
                                                 float* __restrict__ a_dst) {
  int n = blockIdx.x * 256 + threadIdx.x;
  if (n >= NN) return;
  const _Float16* hp = &h2[(size_t)n * F2];
  float s = 0.f, d = 0.f;
  #pragma unroll
  for (int c = 0; c < F2; ++c) {
    float v = (float)hp[c];
    s += v * att_s[c];
    d += v * att_d[c];
  }
  a_src[n] = s; a_dst[n] = d;
}

// ---------------- layer2 aggregation + bias + log_softmax: single-pass softmax, fp16 gather ----
__global__ __launch_bounds__(256) void agg2_kernel(const _Float16* __restrict__ h2, const float* __restrict__ a_src,
                                                   const float* __restrict__ a_dst, const int* __restrict__ offs,
                                                   const int* __restrict__ csr, const float* __restrict__ b2,
                                                   float* __restrict__ out) {
  const int wid = threadIdx.x >> 6, lane = threadIdx.x & 63;
  const int n = blockIdx.x * 4 + wid;
  if (n >= NN) return;
  const int beg = offs[n], end = offs[n + 1];
  const float adst = a_dst[n];
  // lanes 0..56 = (group g=lane/19, channel c=lane%19), 3 edge-groups, 2-edge unroll per group
  const int g = lane / 19;          // 0..3 (g==3 idle)
  const int c = lane - g * 19;
  float acc = 0.f, ls = 0.f;
  if (g < 3) {
    int e = beg + g;
    for (; e + 3 < end; e += 6) {   // this group's edges: e and e+3
      int s0 = csr[e], s1 = csr[e + 3];
      float a0 = a_src[s0] + adst;
      float a1 = a_src[s1] + adst;
      a0 = a0 > 0.f ? a0 : 0.2f * a0;
      a1 = a1 > 0.f ? a1 : 0.2f * a1;
      float w0 = __expf(a0), w1 = __expf(a1);
      float v0 = (float)h2[(size_t)s0 * F2 + c];
      float v1 = (float)h2[(size_t)s1 * F2 + c];
      ls += w0 + w1;
      acc += w0 * v0 + w1 * v1;
    }
    if (e < end) {
      int s0 = csr[e];
      float a0 = a_src[s0] + adst;
      a0 = a0 > 0.f ? a0 : 0.2f * a0;
      float w0 = __expf(a0);
      ls += w0;
      acc += w0 * (float)h2[(size_t)s0 * F2 + c];
    }
  }
  // merge the 3 groups: lane c collects from lanes c, c+19, c+38
  float acc_t = __shfl(acc, c, 64) + __shfl(acc, c + 19, 64) + __shfl(acc, c + 38, 64);
  float ls_t  = __shfl(ls, c, 64) + __shfl(ls, c + 19, 64) + __shfl(ls, c + 38, 64);
  const bool act = lane < F2;
  float o = acc_t / (ls_t + 1e-16f) + (act ? b2[lane] : 0.f);
  // log_softmax across lanes 0..18 (use lanes 0..31 reduce)
  float v = act ? o : -INFINITY;
  float mx = v;
  #pragma unroll
  for (int off = 16; off >= 1; off >>= 1) mx = fmaxf(mx, __shfl_xor(mx, off, 32));
  float se = act ? __expf(v - mx) : 0.f;
  float sum = se;
  #pragma unroll
  for (int off = 16; off >= 1; off >>= 1) sum += __shfl_xor(sum, off, 32);
  if (act) out[(size_t)n * F2 + lane] = (o - mx) - logf(sum);
}

extern "C" void kernel_launch(void* const* d_in, const int* in_sizes, int n_in,
                              void* d_out, int out_size, void* d_ws, size_t ws_size,
                              hipStream_t stream) {
  const float* x   = (const float*)d_in[0];
  const int* ei    = (const int*)d_in[1];
  const float* W1  = (const float*)d_in[2];
  const float* as1 = (const float*)d_in[3];
  const float* ad1 = (const float*)d_in[4];
  const float* b1  = (const float*)d_in[5];
  const float* W2  = (const float*)d_in[6];
  const float* as2 = (const float*)d_in[7];
  const float* ad2 = (const float*)d_in[8];
  const float* b2  = (const float*)d_in[9];
  float* out = (float*)d_out;

  const int* srcp = ei;
  const int* dstp = ei + EE;

  char* p = (char*)d_ws;
  auto alloc = [&](size_t bytes) { char* r = p; p += (bytes + 255) & ~(size_t)255; return r; };
  float*    h1    = (float*)alloc((size_t)NN * F1 * 4);
  _Float16* h1h   = (_Float16*)alloc((size_t)NN * F1 * 2);
  _Float16* act1h = (_Float16*)alloc((size_t)NN * F1 * 2);
  float*    a_s1  = (float*)alloc((size_t)NN * NH * 4);
  float*    a_d1  = (float*)alloc((size_t)NN * NH * 4);
  _Float16* h2h   = (_Float16*)alloc((size_t)NN * F2 * 2);
  float*    a_s2  = (float*)alloc((size_t)NN * 4);
  float*    a_d2  = (float*)alloc((size_t)NN * 4);
  int*      deg   = (int*)alloc((size_t)NN * 4);
  int*      offs  = (int*)alloc((size_t)(NN + 1) * 4);
  int*      cnt   = (int*)alloc((size_t)NN * 4);
  int*      csr   = (int*)alloc((size_t)ET * 4);
  int*      bsum  = (int*)alloc((size_t)SCB * 4);
  int*      tops  = (int*)alloc((size_t)SCB * 4);
  __bf16*   Wth   = (__bf16*)alloc((size_t)128 * 1024 * 2);
  __bf16*   Wtl   = (__bf16*)alloc((size_t)128 * 1024 * 2);

  hipMemsetAsync(deg, 0, (size_t)NN * 4, stream);
  hipMemsetAsync(cnt, 0, (size_t)NN * 4, stream);

  int eb = (ET + 255) / 256;
  deg_kernel<<<eb, 256, 0, stream>>>(dstp, deg);
  scan_block<<<SCB, 256, 0, stream>>>(deg, offs, bsum);
  scan_tops<<<1, 512, 0, stream>>>(bsum, tops, offs);
  scan_add<<<SCB, 256, 0, stream>>>(offs, tops);
  fill_kernel<<<eb, 256, 0, stream>>>(srcp, dstp, offs, cnt, csr);

  wsplit_kernel<<<(1024 * 128 + 255) / 256, 256, 0, stream>>>(W1, Wth, Wtl);
  gemm1_mfma<<<(NN + 127) / 128, 256, 0, stream>>>(x, Wth, Wtl, h1, NN);
  a1_kernel<<<(NN * NH + 255) / 256, 256, 0, stream>>>(h1, as1, ad1, a_s1, a_d1, h1h);
  agg1_kernel<<<(NN + 3) / 4, 256, 0, stream>>>(h1h, a_s1, a_d1, offs, csr, b1, act1h);

  gemm2_kernel<<<(NN * F2 + 255) / 256, 256, 0, stream>>>(act1h, W2, h2h);
  a2_kernel<<<(NN + 255) / 256, 256, 0, stream>>>(h2h, as2, ad2, a_s2, a_d2);
  agg2_kernel<<<(NN + 3) / 4, 256, 0, stream>>>(h2h, a_s2, a_d2, offs, csr, b2, out);
}